// Round 15
// baseline (156.323 us; speedup 1.0000x reference)
//
#include <hip/hip_runtime.h>
#include <math.h>

// EqualtimeLayer: per (b,post): sort 1024 events by t = spike[b][pre]+delay[pre][post],
// prefix-sum (w, w*t) in sorted order, candidate tmp_k=(theta+cumwt)/cumw valid iff
// cumw>0 && tmp>=t_k && (k==last || tmp<=t_{k+1}); output = min valid tmp.
//
// R15 = R13 skeleton + barrier-free local fixup in the common path:
// thread p reads the pre-fixup element at p -> its bucket [bas,cn); cn==1 is
// already correct; cn>1 selects the rank-(p-bas) element via O(cn^2) in-register
// rank scan (lam~0.78, cn mostly 1-2). Drops the gather->barrier->rewrite->
// barrier->re-read round trip (7 -> 5 barriers/batch), the hole-pad stores,
// and the post-fixup re-reads. t_{p+1} via shfl_down + 4-float LDS exchange on
// the existing partial-sum barrier. Valid candidates are provably <= minExcl,
// so done <=> any candidate. Rare paths (N>256, no crossing < 0.625) keep the
// proven R13 chunked run_epoch with carried prefix sums - bit-exact overall.

#define B_TOT 32
#define PRE 1024
#define POST 1024
#define NB 512
#define TPB 256
#define EPT 4
#define BPW 8
#define CHUNK 256
#define TCUTF 0.625f
#define BSCALE 819.2f      // 512 buckets over [0, 0.625)

// ---- DPP helpers (gfx9 encodings) ----
template<int CTRL, int MASK>
__device__ __forceinline__ int dpp_add_i32(int v) {
    return v + __builtin_amdgcn_update_dpp(0, v, CTRL, MASK, 0xf, true);
}
template<int CTRL, int MASK>
__device__ __forceinline__ float dpp_add_f32(float v) {
    int t = __builtin_amdgcn_update_dpp(0, __float_as_int(v), CTRL, MASK, 0xf, true);
    return v + __int_as_float(t);
}
template<int CTRL>
__device__ __forceinline__ float dpp_min_f32(float v) {
    int t = __builtin_amdgcn_update_dpp(__float_as_int(v), __float_as_int(v), CTRL, 0xf, 0xf, false);
    return fminf(v, __int_as_float(t));
}
__device__ __forceinline__ int wave_iscan_i32(int v) {
    v = dpp_add_i32<0x111, 0xf>(v);
    v = dpp_add_i32<0x112, 0xf>(v);
    v = dpp_add_i32<0x114, 0xf>(v);
    v = dpp_add_i32<0x118, 0xf>(v);
    v = dpp_add_i32<0x142, 0xa>(v);
    v = dpp_add_i32<0x143, 0xc>(v);
    return v;
}
__device__ __forceinline__ float wave_iscan_f32(float v) {
    v = dpp_add_f32<0x111, 0xf>(v);
    v = dpp_add_f32<0x112, 0xf>(v);
    v = dpp_add_f32<0x114, 0xf>(v);
    v = dpp_add_f32<0x118, 0xf>(v);
    v = dpp_add_f32<0x142, 0xa>(v);
    v = dpp_add_f32<0x143, 0xc>(v);
    return v;
}
__device__ __forceinline__ float wave_min_f32(float v) {
    v = fminf(v, __shfl_down(v, 32));
    v = fminf(v, __shfl_down(v, 16));
    v = dpp_min_f32<0x140>(v);
    v = dpp_min_f32<0x141>(v);
    v = dpp_min_f32<0x4E>(v);
    v = dpp_min_f32<0xB1>(v);
    return v;
}
__device__ __forceinline__ int clampb(int k) {
    return k < 0 ? 0 : (k > NB - 1 ? NB - 1 : k);
}
__device__ __forceinline__ float fmin4(const float* a) {
    return fminf(fminf(a[0], a[1]), fminf(a[2], a[3]));
}

// Single-wave exclusive scan of NB 32-bit counts (call from wave 0 only).
// Conflict-free int4 reads at [lane]/[lane+64]; split-halves prefix.
// Writes packed (off<<12|cnt) into pck. Returns total.
__device__ __forceinline__ int scan_counts(const int* raw, int* pck, int lane) {
    int4 a = reinterpret_cast<const int4*>(raw)[lane];
    int4 bq = reinterpret_cast<const int4*>(raw)[lane + 64];
    int c1[4] = {a.x, a.y, a.z, a.w};
    int c2[4] = {bq.x, bq.y, bq.z, bq.w};
    int ls1[4], ls2[4];
    int s1 = 0, s2 = 0;
#pragma unroll
    for (int j = 0; j < 4; ++j) { s1 += c1[j]; ls1[j] = s1; }
#pragma unroll
    for (int j = 0; j < 4; ++j) { s2 += c2[j]; ls2[j] = s2; }
    int x1 = wave_iscan_i32(s1);
    int x2 = wave_iscan_i32(s2);
    int tot1 = __builtin_amdgcn_readlane(x1, 63);
    int e1 = x1 - s1;
    int e2 = tot1 + x2 - s2;
    int o1[4], o2[4];
#pragma unroll
    for (int j = 0; j < 4; ++j) {
        o1[j] = ((e1 + ls1[j] - c1[j]) << 12) | c1[j];
        o2[j] = ((e2 + ls2[j] - c2[j]) << 12) | c2[j];
    }
    reinterpret_cast<int4*>(pck)[lane]      = make_int4(o1[0], o1[1], o1[2], o1[3]);
    reinterpret_cast<int4*>(pck)[lane + 64] = make_int4(o2[0], o2[1], o2[2], o2[3]);
    return tot1 + __builtin_amdgcn_readlane(x2, 63);
}

// Block-cooperative chunked solve (R8-proven; rare paths only).
__device__ __forceinline__ bool run_epoch(
    float* s_t, float* s_w, const int* pck, float* s_fw, float* s_fwt, float* s_red,
    int cStart, int cEnd, int posLo, int posValidEnd,
    float t0f, int baseOff, float tEnd, float theta,
    int tid, int lane, int wid, float& cumW, float& cumWT, float& mAll)
{
    for (int c0 = cStart; c0 < cEnd; c0 += CHUNK) {
        const int next = c0 + CHUNK;
        const int p = c0 + tid;
        const bool valid = (p >= posLo);

        float e_t = s_t[p], e_w = s_w[p];
        int np = -1;
        if (valid) {
            int k = clampb((int)((e_t - t0f) * BSCALE));
            int pk = pck[k];
            int bas = (pk >> 12) + baseOff, cn = pk & 0xfff;
            if (bas >= c0 && cn > 1) {
                int r = 0;
                for (int q = bas; q < bas + cn; ++q) {
                    float tq = s_t[q];
                    r += ((tq < e_t) || (tq == e_t && q < p)) ? 1 : 0;
                }
                int tgt = bas + r;
                if (tgt != p) np = tgt;
            }
        }
        int np2 = -1; float e2t = 0.f, e2w = 0.f;
        if (tid < 64) {
            int p2 = next + tid;
            if (p2 < cEnd && p2 >= posLo) {
                e2t = s_t[p2]; e2w = s_w[p2];
                int k = clampb((int)((e2t - t0f) * BSCALE));
                int pk = pck[k];
                int bas = (pk >> 12) + baseOff, cn = pk & 0xfff;
                if (bas >= c0 && bas < next && cn > 1) {
                    int r = 0;
                    for (int q = bas; q < bas + cn; ++q) {
                        float tq = s_t[q];
                        r += ((tq < e2t) || (tq == e2t && q < p2)) ? 1 : 0;
                    }
                    int tgt = bas + r;
                    if (tgt != p2) np2 = tgt;
                }
            }
        }
        __syncthreads();                                   // gathers done
        if (np  >= 0) { s_t[np]  = e_t;  s_w[np]  = e_w; }
        if (np2 >= 0) { s_t[np2] = e2t; s_w[np2] = e2w; }
        __syncthreads();                                   // fixup visible

        float t_next = tEnd;
        if (next < cEnd) {
            float tx = s_t[next];
            int k = clampb((int)((tx - t0f) * BSCALE));
            int pk = pck[k];
            int bas = (pk >> 12) + baseOff, cn = pk & 0xfff;
            t_next = tx;
            if (bas >= next) {
                for (int q = bas; q < bas + cn; ++q) t_next = fminf(t_next, s_t[q]);
            }
        }

        float t_p = s_t[p];
        float w_p = valid ? s_w[p] : 0.f;
        float aw = w_p, awt = w_p * t_p;
        float xw  = wave_iscan_f32(aw);
        float xwt = wave_iscan_f32(awt);
        if (lane == 63) { s_fw[wid] = xw; s_fwt[wid] = xwt; }
        float tn = (p == PRE - 1) ? INFINITY
                 : (tid == TPB - 1) ? t_next : s_t[p + 1];
        __syncthreads();                                   // partials visible
        float W = cumW, WT = cumWT;
        for (int k2 = 0; k2 < wid; ++k2) { W += s_fw[k2]; WT += s_fwt[k2]; }
        W += xw; WT += xwt;
        cumW  += s_fw[0] + s_fw[1] + s_fw[2] + s_fw[3];
        cumWT += s_fwt[0] + s_fwt[1] + s_fwt[2] + s_fwt[3];

        float mc = INFINITY;
        if (valid && p < posValidEnd && W > 0.f) {
            float tmp = (theta + WT) * __builtin_amdgcn_rcpf(W);
            if (tmp >= t_p && tmp <= tn) mc = tmp;
        }
        mc = wave_min_f32(mc);
        if (lane == 0) s_red[wid] = mc;
        __syncthreads();                                   // mins visible
        mAll = fminf(mAll,
               fminf(fminf(s_red[0], s_red[1]), fminf(s_red[2], s_red[3])));
        if (mAll <= t_next) return true;
    }
    return false;
}

__global__ __launch_bounds__(TPB, 8) void equaltime_kernel(
    const float* __restrict__ spikes,     // [B][PRE]
    const float* __restrict__ weights,    // [PRE][POST]
    const float* __restrict__ delays,     // [PRE][POST]
    const float* __restrict__ thresholds, // [POST]
    float* __restrict__ out)              // [B][POST]
{
    __shared__ __align__(16) float s_t[PRE];   // 4 KB
    __shared__ __align__(16) float s_w[PRE];   // 4 KB
    __shared__ __align__(16) int   s_raw[NB];  // 2 KB raw counts (hist target)
    __shared__ __align__(16) int   s_pck[NB];  // 2 KB packed (off<<12|cnt)
    __shared__ float s_fw[4], s_fwt[4];
    __shared__ float s_red[4];
    __shared__ float s_tn[4];                  // cross-wave t_{p+1} exchange
    __shared__ int   s_N;

    const int tid  = threadIdx.x;
    const int lane = tid & 63;
    const int wid  = tid >> 6;

    // XCD-contiguous swizzle for weight/delay L2 locality
    const int bx   = blockIdx.x;
    const int sbx  = (bx & 7) * 512 + (bx >> 3);
    const int post = sbx >> 2;            // 4 WGs per post
    const int b0   = (sbx & 3) * BPW;
    const float theta = thresholds[post];

    float dly[EPT], wgt[EPT];
#pragma unroll
    for (int j = 0; j < EPT; ++j) {
        int pre = tid * EPT + j;
        dly[j] = delays[pre * POST + post];
        wgt[j] = weights[pre * POST + post];
    }

    // zero raw counts once (subsequent batches re-zero in the scatter slot)
    reinterpret_cast<int2*>(s_raw)[tid] = make_int2(0, 0);
    __syncthreads();

    for (int bi = 0; bi < BPW; ++bi) {
        const int b = b0 + bi;

        // ---- times; hist of t<TCUT into s_raw; min of the rest ----
        float4 sp = *reinterpret_cast<const float4*>(spikes + b * PRE + tid * EPT);
        float tv[EPT] = {sp.x + dly[0], sp.y + dly[1], sp.z + dly[2], sp.w + dly[3]};
        int bkt[EPT], rnk[EPT];
        float mloc = INFINITY;
#pragma unroll
        for (int j = 0; j < EPT; ++j) {
            int k = (int)(tv[j] * BSCALE);
            bkt[j] = k;
            if (k < NB) rnk[j] = atomicAdd(&s_raw[k], 1);
            else        mloc = fminf(mloc, tv[j]);
        }
        mloc = wave_min_f32(mloc);
        __syncthreads();                                   // B1: counts final

        if (lane == 0) s_red[wid] = mloc;                  // post-B1 write,
                                                           // post-B2 read
        if (wid == 0) {                                    // single-wave scan
            int n = scan_counts(s_raw, s_pck, lane);
            if (lane == 0) s_N = n;
        }
        __syncthreads();                                   // B2: pck+N+s_red visible

        const int   N_low = s_N;
        const float minExcl = fmin4(s_red);
        // ---- scatter included (reads s_pck); wave1 zeroes s_raw ----
#pragma unroll
        for (int j = 0; j < EPT; ++j) {
            if (bkt[j] < NB) {
                int pos = (s_pck[bkt[j]] >> 12) + rnk[j];
                s_t[pos] = tv[j];
                s_w[pos] = wgt[j];
            }
        }
        if (wid == 1) {   // all s_raw reads completed at B2; contiguous writes
            reinterpret_cast<int4*>(s_raw)[lane]      = make_int4(0, 0, 0, 0);
            reinterpret_cast<int4*>(s_raw)[lane + 64] = make_int4(0, 0, 0, 0);
        }
        __syncthreads();                                   // B3: scatter+zero visible

        const bool okN = (N_low <= CHUNK);

        // ---- local fixup: thread p derives its post-fixup (t,w) with no
        //      rewrite / extra barriers. Holes (p>=N_low) are (minExcl, 0). ----
        float myT = minExcl, myW = 0.f;
        if (okN && tid < N_low) {
            float tp = s_t[tid];
            int k  = (int)(tp * BSCALE);       // bit-identical to scatter's calc
            int pk = s_pck[k];
            int bas = pk >> 12, cn = pk & 0xfff;
            if (cn == 1) {
                myT = tp; myW = s_w[tid];
            } else {
                int sel = tid - bas;
                for (int q = bas; q < bas + cn; ++q) {
                    float tq = s_t[q];
                    int r = 0;
                    for (int u = bas; u < bas + cn; ++u) {
                        float tu = s_t[u];
                        r += ((tu < tq) || (tu == tq && u < q)) ? 1 : 0;
                    }
                    if (r == sel) { myT = tq; myW = s_w[q]; }
                }
            }
        }

        // ---- block scan of (w, w*t); t_{p+1} via shfl + 4-float exchange ----
        float xw  = wave_iscan_f32(myW);
        float xwt = wave_iscan_f32(myW * myT);
        if (lane == 63) { s_fw[wid] = xw; s_fwt[wid] = xwt; }
        if (lane == 0)  s_tn[wid] = myT;
        float tshuf = __shfl_down(myT, 1);
        __syncthreads();                                   // Bd: partials+tn visible
        float W = 0.f, WT = 0.f;
        for (int k2 = 0; k2 < wid; ++k2) { W += s_fw[k2]; WT += s_fwt[k2]; }
        const float totW  = s_fw[0] + s_fw[1] + s_fw[2] + s_fw[3];
        const float totWT = s_fwt[0] + s_fwt[1] + s_fwt[2] + s_fwt[3];
        W += xw; WT += xwt;
        float tn = (lane == 63) ? ((wid < 3) ? s_tn[wid + 1] : minExcl) : tshuf;

        // ---- candidate + block min (any valid candidate is <= minExcl) ----
        float mc = INFINITY;
        if (okN && tid < N_low && W > 0.f) {
            float tmp = (theta + WT) * __builtin_amdgcn_rcpf(W);
            if (tmp >= myT && tmp <= tn) mc = tmp;
        }
        mc = wave_min_f32(mc);
        if (lane == 0) s_red[wid] = mc;
        __syncthreads();                                   // Be: mins visible
        float mAll = fmin4(s_red);
        bool done = okN && (mAll <= minExcl);

        if (!done) {
            float cumW = totW, cumWT = totWT;
            if (!okN) {
                // overflow (P~5e-6): hole-pad + proven chunked solve of included
                cumW = 0.f; cumWT = 0.f; mAll = INFINITY;
                const int roundup = (N_low + CHUNK - 1) & ~(CHUNK - 1);
                int h = N_low + tid;
                if (h < roundup) { s_t[h] = minExcl; s_w[h] = 0.f; }
                __syncthreads();
                done = run_epoch(s_t, s_w, s_pck, s_fw, s_fwt, s_red,
                                 0, roundup, 0, N_low, 0.f, 0, minExcl, theta,
                                 tid, lane, wid, cumW, cumWT, mAll);
            }
            // rare exact fallback: sort & process the excluded tail
            if (!done && N_low < PRE) {
                // s_raw is zeroed; s_pck dead. Reuse bkt/rnk registers.
#pragma unroll
                for (int j = 0; j < EPT; ++j) {
                    if (bkt[j] >= NB) {
                        int k2 = clampb((int)((tv[j] - TCUTF) * BSCALE));
                        bkt[j] = NB + k2;          // remember tail bucket
                        rnk[j] = atomicAdd(&s_raw[k2], 1);
                    }
                }
                __syncthreads();                           // counts final
                if (wid == 0) (void)scan_counts(s_raw, s_pck, lane);
                __syncthreads();                           // pck visible
#pragma unroll
                for (int j = 0; j < EPT; ++j) {
                    if (bkt[j] >= NB) {
                        int k2 = bkt[j] - NB;
                        int pos = N_low + (s_pck[k2] >> 12) + rnk[j];
                        s_t[pos] = tv[j];
                        s_w[pos] = wgt[j];
                    }
                }
                if (wid == 1) {   // re-zero raw for the next batch
                    reinterpret_cast<int4*>(s_raw)[lane]      = make_int4(0, 0, 0, 0);
                    reinterpret_cast<int4*>(s_raw)[lane + 64] = make_int4(0, 0, 0, 0);
                }
                __syncthreads();                           // scatter+zero visible
                run_epoch(s_t, s_w, s_pck, s_fw, s_fwt, s_red,
                          N_low & ~(CHUNK - 1), PRE, N_low, PRE,
                          TCUTF, N_low, INFINITY, theta,
                          tid, lane, wid, cumW, cumWT, mAll);
            }
        }

        if (tid == 0) out[b * POST + post] = mAll;
        // No trailing barrier: next batch's hist atomics target s_raw, whose
        // zeroing was barrier-ordered before any post-barrier reader; all
        // s_t/s_w/s_pck reads this batch completed before Be / epoch barriers.
    }
}

extern "C" void kernel_launch(void* const* d_in, const int* in_sizes, int n_in,
                              void* d_out, int out_size, void* d_ws, size_t ws_size,
                              hipStream_t stream) {
    const float* spikes     = (const float*)d_in[0]; // [32,1024]
    const float* weights    = (const float*)d_in[1]; // [1024,1024]
    const float* delays     = (const float*)d_in[2]; // [1024,1024]
    const float* thresholds = (const float*)d_in[3]; // [1024]
    float* outp = (float*)d_out;                     // [32,1024]

    dim3 grid(POST * (B_TOT / BPW)); // 4096 workgroups
    dim3 block(TPB);
    equaltime_kernel<<<grid, block, 0, stream>>>(spikes, weights, delays, thresholds, outp);
}

// Round 16
// 138.154 us; speedup vs baseline: 1.1315x; 1.1315x over previous
//
#include <hip/hip_runtime.h>
#include <math.h>

// EqualtimeLayer: per (b,post): sort 1024 events by t = spike[b][pre]+delay[pre][post],
// prefix-sum (w, w*t) in sorted order, candidate tmp_k=(theta+cumwt)/cumw valid iff
// cumw>0 && tmp>=t_k && (k==last || tmp<=t_{k+1}); output = min valid tmp.
//
// R16 = R13 exactly (best measured: 78.5us rocprof; conflict-free split-halves
// count scan, BPW=8, spill-free) + next-batch spike-row prefetch (the float4
// spike load's ~200cy L2 latency was exposed at the top of each batch; issue
// batch bi+1's load at the top of batch bi -> a full batch body to complete).
// Only events t < 0.625 (~20%) are bucketed/sorted (512 buckets); the rest
// contribute their exact min time (epoch-0 boundary). Crossing t*~0.49 =>
// epoch 0 is one 256-chunk with exact early exit. Fallback = tail-only
// re-sort reusing bkt/rnk registers (no extra live state -> no spill).

#define B_TOT 32
#define PRE 1024
#define POST 1024
#define NB 512
#define TPB 256
#define EPT 4
#define BPW 8
#define CHUNK 256
#define TCUTF 0.625f
#define BSCALE 819.2f      // 512 buckets over [0, 0.625)

// ---- DPP helpers (gfx9 encodings) ----
template<int CTRL, int MASK>
__device__ __forceinline__ int dpp_add_i32(int v) {
    return v + __builtin_amdgcn_update_dpp(0, v, CTRL, MASK, 0xf, true);
}
template<int CTRL, int MASK>
__device__ __forceinline__ float dpp_add_f32(float v) {
    int t = __builtin_amdgcn_update_dpp(0, __float_as_int(v), CTRL, MASK, 0xf, true);
    return v + __int_as_float(t);
}
template<int CTRL>
__device__ __forceinline__ float dpp_min_f32(float v) {
    int t = __builtin_amdgcn_update_dpp(__float_as_int(v), __float_as_int(v), CTRL, 0xf, 0xf, false);
    return fminf(v, __int_as_float(t));
}
__device__ __forceinline__ int wave_iscan_i32(int v) {
    v = dpp_add_i32<0x111, 0xf>(v);
    v = dpp_add_i32<0x112, 0xf>(v);
    v = dpp_add_i32<0x114, 0xf>(v);
    v = dpp_add_i32<0x118, 0xf>(v);
    v = dpp_add_i32<0x142, 0xa>(v);
    v = dpp_add_i32<0x143, 0xc>(v);
    return v;
}
__device__ __forceinline__ float wave_iscan_f32(float v) {
    v = dpp_add_f32<0x111, 0xf>(v);
    v = dpp_add_f32<0x112, 0xf>(v);
    v = dpp_add_f32<0x114, 0xf>(v);
    v = dpp_add_f32<0x118, 0xf>(v);
    v = dpp_add_f32<0x142, 0xa>(v);
    v = dpp_add_f32<0x143, 0xc>(v);
    return v;
}
__device__ __forceinline__ float wave_min_f32(float v) {
    v = fminf(v, __shfl_down(v, 32));
    v = fminf(v, __shfl_down(v, 16));
    v = dpp_min_f32<0x140>(v);
    v = dpp_min_f32<0x141>(v);
    v = dpp_min_f32<0x4E>(v);
    v = dpp_min_f32<0xB1>(v);
    return v;
}
__device__ __forceinline__ int clampb(int k) {
    return k < 0 ? 0 : (k > NB - 1 ? NB - 1 : k);
}

// Redundant (every wave identical) exclusive scan of NB 32-bit counts.
// Conflict-free reads: int4 at [lane] and [lane+64]; split-halves prefix
// (half-2 offset by half-1 total). Wave 0 writes packed (off<<12|cnt) into
// pck. Returns total (uniform).
__device__ __forceinline__ int scan_counts(const int* raw, int* pck, int lane, int wid) {
    int4 a = reinterpret_cast<const int4*>(raw)[lane];
    int4 bq = reinterpret_cast<const int4*>(raw)[lane + 64];
    int c1[4] = {a.x, a.y, a.z, a.w};
    int c2[4] = {bq.x, bq.y, bq.z, bq.w};
    int ls1[4], ls2[4];
    int s1 = 0, s2 = 0;
#pragma unroll
    for (int j = 0; j < 4; ++j) { s1 += c1[j]; ls1[j] = s1; }
#pragma unroll
    for (int j = 0; j < 4; ++j) { s2 += c2[j]; ls2[j] = s2; }
    int x1 = wave_iscan_i32(s1);
    int x2 = wave_iscan_i32(s2);
    int tot1 = __builtin_amdgcn_readlane(x1, 63);
    int e1 = x1 - s1;
    int e2 = tot1 + x2 - s2;
    if (wid == 0) {
        int o1[4], o2[4];
#pragma unroll
        for (int j = 0; j < 4; ++j) {
            o1[j] = ((e1 + ls1[j] - c1[j]) << 12) | c1[j];
            o2[j] = ((e2 + ls2[j] - c2[j]) << 12) | c2[j];
        }
        reinterpret_cast<int4*>(pck)[lane]      = make_int4(o1[0], o1[1], o1[2], o1[3]);
        reinterpret_cast<int4*>(pck)[lane + 64] = make_int4(o2[0], o2[1], o2[2], o2[3]);
    }
    return tot1 + __builtin_amdgcn_readlane(x2, 63);
}

// Block-cooperative chunked solve (R8-proven, unchanged).
__device__ __forceinline__ bool run_epoch(
    float* s_t, float* s_w, const int* pck, float* s_fw, float* s_fwt, float* s_red,
    int cStart, int cEnd, int posLo, int posValidEnd,
    float t0f, int baseOff, float tEnd, float theta,
    int tid, int lane, int wid, float& cumW, float& cumWT, float& mAll)
{
    for (int c0 = cStart; c0 < cEnd; c0 += CHUNK) {
        const int next = c0 + CHUNK;
        const int p = c0 + tid;
        const bool valid = (p >= posLo);

        float e_t = s_t[p], e_w = s_w[p];
        int np = -1;
        if (valid) {
            int k = clampb((int)((e_t - t0f) * BSCALE));
            int pk = pck[k];
            int bas = (pk >> 12) + baseOff, cn = pk & 0xfff;
            if (bas >= c0 && cn > 1) {
                int r = 0;
                for (int q = bas; q < bas + cn; ++q) {
                    float tq = s_t[q];
                    r += ((tq < e_t) || (tq == e_t && q < p)) ? 1 : 0;
                }
                int tgt = bas + r;
                if (tgt != p) np = tgt;
            }
        }
        int np2 = -1; float e2t = 0.f, e2w = 0.f;
        if (tid < 64) {
            int p2 = next + tid;
            if (p2 < cEnd && p2 >= posLo) {
                e2t = s_t[p2]; e2w = s_w[p2];
                int k = clampb((int)((e2t - t0f) * BSCALE));
                int pk = pck[k];
                int bas = (pk >> 12) + baseOff, cn = pk & 0xfff;
                if (bas >= c0 && bas < next && cn > 1) {
                    int r = 0;
                    for (int q = bas; q < bas + cn; ++q) {
                        float tq = s_t[q];
                        r += ((tq < e2t) || (tq == e2t && q < p2)) ? 1 : 0;
                    }
                    int tgt = bas + r;
                    if (tgt != p2) np2 = tgt;
                }
            }
        }
        __syncthreads();                                   // gathers done
        if (np  >= 0) { s_t[np]  = e_t;  s_w[np]  = e_w; }
        if (np2 >= 0) { s_t[np2] = e2t; s_w[np2] = e2w; }
        __syncthreads();                                   // fixup visible

        float t_next = tEnd;
        if (next < cEnd) {
            float tx = s_t[next];
            int k = clampb((int)((tx - t0f) * BSCALE));
            int pk = pck[k];
            int bas = (pk >> 12) + baseOff, cn = pk & 0xfff;
            t_next = tx;
            if (bas >= next) {
                for (int q = bas; q < bas + cn; ++q) t_next = fminf(t_next, s_t[q]);
            }
        }

        float t_p = s_t[p];
        float w_p = valid ? s_w[p] : 0.f;
        float aw = w_p, awt = w_p * t_p;
        float xw  = wave_iscan_f32(aw);
        float xwt = wave_iscan_f32(awt);
        if (lane == 63) { s_fw[wid] = xw; s_fwt[wid] = xwt; }
        float tn = (p == PRE - 1) ? INFINITY
                 : (tid == TPB - 1) ? t_next : s_t[p + 1];
        __syncthreads();                                   // partials visible
        float W = cumW, WT = cumWT;
        for (int k2 = 0; k2 < wid; ++k2) { W += s_fw[k2]; WT += s_fwt[k2]; }
        W += xw; WT += xwt;
        cumW  += s_fw[0] + s_fw[1] + s_fw[2] + s_fw[3];
        cumWT += s_fwt[0] + s_fwt[1] + s_fwt[2] + s_fwt[3];

        float mc = INFINITY;
        if (valid && p < posValidEnd && W > 0.f) {
            float tmp = (theta + WT) * __builtin_amdgcn_rcpf(W);
            if (tmp >= t_p && tmp <= tn) mc = tmp;
        }
        mc = wave_min_f32(mc);
        if (lane == 0) s_red[wid] = mc;
        __syncthreads();                                   // mins visible
        mAll = fminf(mAll,
               fminf(fminf(s_red[0], s_red[1]), fminf(s_red[2], s_red[3])));
        if (mAll <= t_next) return true;
    }
    return false;
}

__global__ __launch_bounds__(TPB, 8) void equaltime_kernel(
    const float* __restrict__ spikes,     // [B][PRE]
    const float* __restrict__ weights,    // [PRE][POST]
    const float* __restrict__ delays,     // [PRE][POST]
    const float* __restrict__ thresholds, // [POST]
    float* __restrict__ out)              // [B][POST]
{
    __shared__ __align__(16) float s_t[PRE];   // 4 KB
    __shared__ __align__(16) float s_w[PRE];   // 4 KB
    __shared__ __align__(16) int   s_raw[NB];  // 2 KB raw counts (hist target)
    __shared__ __align__(16) int   s_pck[NB];  // 2 KB packed (off<<12|cnt)
    __shared__ float s_fw[4], s_fwt[4];
    __shared__ float s_red[4];

    const int tid  = threadIdx.x;
    const int lane = tid & 63;
    const int wid  = tid >> 6;

    // XCD-contiguous swizzle for weight/delay L2 locality
    const int bx   = blockIdx.x;
    const int sbx  = (bx & 7) * 512 + (bx >> 3);
    const int post = sbx >> 2;            // 4 WGs per post
    const int b0   = (sbx & 3) * BPW;
    const float theta = thresholds[post];

    float dly[EPT], wgt[EPT];
#pragma unroll
    for (int j = 0; j < EPT; ++j) {
        int pre = tid * EPT + j;
        dly[j] = delays[pre * POST + post];
        wgt[j] = weights[pre * POST + post];
    }

    // zero raw counts once (subsequent batches re-zero in the scatter slot)
    reinterpret_cast<int2*>(s_raw)[tid] = make_int2(0, 0);

    // prefetch batch 0's spike row (issued before the prologue barrier)
    float4 sp = *reinterpret_cast<const float4*>(spikes + b0 * PRE + tid * EPT);
    __syncthreads();

    for (int bi = 0; bi < BPW; ++bi) {
        const int b = b0 + bi;

        // ---- prefetch NEXT batch's spike row (full batch body to complete) ----
        float4 spn;
        if (bi + 1 < BPW) {
            spn = *reinterpret_cast<const float4*>(
                spikes + (b + 1) * PRE + tid * EPT);
        }

        // ---- times; hist of t<TCUT into s_raw; min of the rest ----
        float tv[EPT] = {sp.x + dly[0], sp.y + dly[1], sp.z + dly[2], sp.w + dly[3]};
        int bkt[EPT], rnk[EPT];
        float mloc = INFINITY;
#pragma unroll
        for (int j = 0; j < EPT; ++j) {
            int k = (int)(tv[j] * BSCALE);
            bkt[j] = k;
            if (k < NB) rnk[j] = atomicAdd(&s_raw[k], 1);
            else        mloc = fminf(mloc, tv[j]);
        }
        mloc = wave_min_f32(mloc);
        __syncthreads();                                   // B1: counts final

        if (lane == 0) s_red[wid] = mloc;                  // post-B1 write,
                                                           // post-B2 read
        const int N_low = scan_counts(s_raw, s_pck, lane, wid); // reads raw only
        __syncthreads();                                   // B2: pck + s_red visible

        const float minExcl = fminf(fminf(s_red[0], s_red[1]),
                                    fminf(s_red[2], s_red[3]));
        // ---- scatter included (reads s_pck); pad holes; wave1 zeroes s_raw ----
#pragma unroll
        for (int j = 0; j < EPT; ++j) {
            if (bkt[j] < NB) {
                int pos = (s_pck[bkt[j]] >> 12) + rnk[j];
                s_t[pos] = tv[j];
                s_w[pos] = wgt[j];
            }
        }
        if (wid == 1) {   // all s_raw reads completed at B2; contiguous writes
            reinterpret_cast<int4*>(s_raw)[lane]      = make_int4(0, 0, 0, 0);
            reinterpret_cast<int4*>(s_raw)[lane + 64] = make_int4(0, 0, 0, 0);
        }
        const int roundup = (N_low + CHUNK - 1) & ~(CHUNK - 1);
        int h = N_low + tid;
        if (h < roundup) { s_t[h] = minExcl; s_w[h] = 0.f; }
        __syncthreads();                                   // B3: scatter+zero visible

        // ---- epoch 0 (typically one chunk, exact early exit) ----
        float cumW = 0.f, cumWT = 0.f, mAll = INFINITY;
        bool done = run_epoch(s_t, s_w, s_pck, s_fw, s_fwt, s_red,
                              0, roundup, 0, N_low, 0.f, 0, minExcl, theta,
                              tid, lane, wid, cumW, cumWT, mAll);

        // ---- rare exact fallback: sort & process the excluded tail ----
        if (!done && N_low < PRE) {
            // s_raw is zeroed; s_pck is dead (epoch 0 finished). Reuse bkt/rnk.
#pragma unroll
            for (int j = 0; j < EPT; ++j) {
                if (bkt[j] >= NB) {
                    int k2 = clampb((int)((tv[j] - TCUTF) * BSCALE));
                    bkt[j] = NB + k2;          // remember tail bucket
                    rnk[j] = atomicAdd(&s_raw[k2], 1);
                }
            }
            __syncthreads();                               // counts final
            (void)scan_counts(s_raw, s_pck, lane, wid);    // wave 0 packs
            __syncthreads();                               // pck visible
#pragma unroll
            for (int j = 0; j < EPT; ++j) {
                if (bkt[j] >= NB) {
                    int k2 = bkt[j] - NB;
                    int pos = N_low + (s_pck[k2] >> 12) + rnk[j];
                    s_t[pos] = tv[j];
                    s_w[pos] = wgt[j];
                }
            }
            if (wid == 1) {   // re-zero raw for the next batch
                reinterpret_cast<int4*>(s_raw)[lane]      = make_int4(0, 0, 0, 0);
                reinterpret_cast<int4*>(s_raw)[lane + 64] = make_int4(0, 0, 0, 0);
            }
            __syncthreads();                               // scatter+zero visible
            run_epoch(s_t, s_w, s_pck, s_fw, s_fwt, s_red,
                      N_low & ~(CHUNK - 1), PRE, N_low, PRE,
                      TCUTF, N_low, INFINITY, theta,
                      tid, lane, wid, cumW, cumWT, mAll);
        }

        if (tid == 0) out[b * POST + post] = mAll;
        sp = spn;   // rotate prefetched spike row into place
        // No trailing barrier: next batch's hist atomics target s_raw, whose
        // zeroing was barrier-ordered before any post-barrier reader.
    }
}

extern "C" void kernel_launch(void* const* d_in, const int* in_sizes, int n_in,
                              void* d_out, int out_size, void* d_ws, size_t ws_size,
                              hipStream_t stream) {
    const float* spikes     = (const float*)d_in[0]; // [32,1024]
    const float* weights    = (const float*)d_in[1]; // [1024,1024]
    const float* delays     = (const float*)d_in[2]; // [1024,1024]
    const float* thresholds = (const float*)d_in[3]; // [1024]
    float* outp = (float*)d_out;                     // [32,1024]

    dim3 grid(POST * (B_TOT / BPW)); // 4096 workgroups
    dim3 block(TPB);
    equaltime_kernel<<<grid, block, 0, stream>>>(spikes, weights, delays, thresholds, outp);
}

// Round 17
// 132.428 us; speedup vs baseline: 1.1804x; 1.0432x over previous
//
#include <hip/hip_runtime.h>
#include <math.h>

// EqualtimeLayer: per (b,post): sort 1024 events by t = spike[b][pre]+delay[pre][post],
// prefix-sum (w, w*t) in sorted order, candidate tmp_k=(theta+cumwt)/cumw valid iff
// cumw>0 && tmp>=t_k && (k==last || tmp<=t_{k+1}); output = min valid tmp.
//
// FINAL (= R13, best measured: 78.5us rocprof, 132us bench, absmax 2e-3):
//  - counting sort of ONLY events t < 0.625 (~20%, 512 buckets over [0,0.625));
//    excluded events contribute their exact min time (epoch-0 boundary)
//  - crossing sits at t*~0.49+-0.05 (E[V(t)]=8.53t^3 vs theta=1) => epoch 0 is
//    one 256-chunk: in-LDS exact rank fixup, DPP block scans of (w, w*t),
//    candidate eval with v_rcp, exact early exit vs minExcl
//  - conflict-free split-halves count scan (int4 at [lane]/[lane+64])
//  - rare exact fallback (no crossing < 0.625): tail-only re-sort with carried
//    prefix sums, reusing bkt/rnk registers (no extra live state -> no spill)
// Structural floor: ~1470 cy/CU/batch = ~700 cy of 7-barrier drain (sort->scan->
// solve dependence) + ~750 cy irreducible issue (hist/scatter/scans). All six
// attempted restructures (wave-per-task, rotating solver, paired batches, local
// fixup, prefetch) regressed via scratch spill or added critical-path work.

#define B_TOT 32
#define PRE 1024
#define POST 1024
#define NB 512
#define TPB 256
#define EPT 4
#define BPW 8
#define CHUNK 256
#define TCUTF 0.625f
#define BSCALE 819.2f      // 512 buckets over [0, 0.625)

// ---- DPP helpers (gfx9 encodings) ----
template<int CTRL, int MASK>
__device__ __forceinline__ int dpp_add_i32(int v) {
    return v + __builtin_amdgcn_update_dpp(0, v, CTRL, MASK, 0xf, true);
}
template<int CTRL, int MASK>
__device__ __forceinline__ float dpp_add_f32(float v) {
    int t = __builtin_amdgcn_update_dpp(0, __float_as_int(v), CTRL, MASK, 0xf, true);
    return v + __int_as_float(t);
}
template<int CTRL>
__device__ __forceinline__ float dpp_min_f32(float v) {
    int t = __builtin_amdgcn_update_dpp(__float_as_int(v), __float_as_int(v), CTRL, 0xf, 0xf, false);
    return fminf(v, __int_as_float(t));
}
__device__ __forceinline__ int wave_iscan_i32(int v) {
    v = dpp_add_i32<0x111, 0xf>(v);
    v = dpp_add_i32<0x112, 0xf>(v);
    v = dpp_add_i32<0x114, 0xf>(v);
    v = dpp_add_i32<0x118, 0xf>(v);
    v = dpp_add_i32<0x142, 0xa>(v);
    v = dpp_add_i32<0x143, 0xc>(v);
    return v;
}
__device__ __forceinline__ float wave_iscan_f32(float v) {
    v = dpp_add_f32<0x111, 0xf>(v);
    v = dpp_add_f32<0x112, 0xf>(v);
    v = dpp_add_f32<0x114, 0xf>(v);
    v = dpp_add_f32<0x118, 0xf>(v);
    v = dpp_add_f32<0x142, 0xa>(v);
    v = dpp_add_f32<0x143, 0xc>(v);
    return v;
}
__device__ __forceinline__ float wave_min_f32(float v) {
    v = fminf(v, __shfl_down(v, 32));
    v = fminf(v, __shfl_down(v, 16));
    v = dpp_min_f32<0x140>(v);
    v = dpp_min_f32<0x141>(v);
    v = dpp_min_f32<0x4E>(v);
    v = dpp_min_f32<0xB1>(v);
    return v;
}
__device__ __forceinline__ int clampb(int k) {
    return k < 0 ? 0 : (k > NB - 1 ? NB - 1 : k);
}

// Redundant (every wave identical) exclusive scan of NB 32-bit counts.
// Conflict-free reads: int4 at [lane] and [lane+64]; split-halves prefix
// (half-2 offset by half-1 total). Wave 0 writes packed (off<<12|cnt) into
// pck. Returns total (uniform).
__device__ __forceinline__ int scan_counts(const int* raw, int* pck, int lane, int wid) {
    int4 a = reinterpret_cast<const int4*>(raw)[lane];
    int4 bq = reinterpret_cast<const int4*>(raw)[lane + 64];
    int c1[4] = {a.x, a.y, a.z, a.w};
    int c2[4] = {bq.x, bq.y, bq.z, bq.w};
    int ls1[4], ls2[4];
    int s1 = 0, s2 = 0;
#pragma unroll
    for (int j = 0; j < 4; ++j) { s1 += c1[j]; ls1[j] = s1; }
#pragma unroll
    for (int j = 0; j < 4; ++j) { s2 += c2[j]; ls2[j] = s2; }
    int x1 = wave_iscan_i32(s1);
    int x2 = wave_iscan_i32(s2);
    int tot1 = __builtin_amdgcn_readlane(x1, 63);
    int e1 = x1 - s1;
    int e2 = tot1 + x2 - s2;
    if (wid == 0) {
        int o1[4], o2[4];
#pragma unroll
        for (int j = 0; j < 4; ++j) {
            o1[j] = ((e1 + ls1[j] - c1[j]) << 12) | c1[j];
            o2[j] = ((e2 + ls2[j] - c2[j]) << 12) | c2[j];
        }
        reinterpret_cast<int4*>(pck)[lane]      = make_int4(o1[0], o1[1], o1[2], o1[3]);
        reinterpret_cast<int4*>(pck)[lane + 64] = make_int4(o2[0], o2[1], o2[2], o2[3]);
    }
    return tot1 + __builtin_amdgcn_readlane(x2, 63);
}

// Block-cooperative chunked solve.
__device__ __forceinline__ bool run_epoch(
    float* s_t, float* s_w, const int* pck, float* s_fw, float* s_fwt, float* s_red,
    int cStart, int cEnd, int posLo, int posValidEnd,
    float t0f, int baseOff, float tEnd, float theta,
    int tid, int lane, int wid, float& cumW, float& cumWT, float& mAll)
{
    for (int c0 = cStart; c0 < cEnd; c0 += CHUNK) {
        const int next = c0 + CHUNK;
        const int p = c0 + tid;
        const bool valid = (p >= posLo);

        float e_t = s_t[p], e_w = s_w[p];
        int np = -1;
        if (valid) {
            int k = clampb((int)((e_t - t0f) * BSCALE));
            int pk = pck[k];
            int bas = (pk >> 12) + baseOff, cn = pk & 0xfff;
            if (bas >= c0 && cn > 1) {
                int r = 0;
                for (int q = bas; q < bas + cn; ++q) {
                    float tq = s_t[q];
                    r += ((tq < e_t) || (tq == e_t && q < p)) ? 1 : 0;
                }
                int tgt = bas + r;
                if (tgt != p) np = tgt;
            }
        }
        int np2 = -1; float e2t = 0.f, e2w = 0.f;
        if (tid < 64) {
            int p2 = next + tid;
            if (p2 < cEnd && p2 >= posLo) {
                e2t = s_t[p2]; e2w = s_w[p2];
                int k = clampb((int)((e2t - t0f) * BSCALE));
                int pk = pck[k];
                int bas = (pk >> 12) + baseOff, cn = pk & 0xfff;
                if (bas >= c0 && bas < next && cn > 1) {
                    int r = 0;
                    for (int q = bas; q < bas + cn; ++q) {
                        float tq = s_t[q];
                        r += ((tq < e2t) || (tq == e2t && q < p2)) ? 1 : 0;
                    }
                    int tgt = bas + r;
                    if (tgt != p2) np2 = tgt;
                }
            }
        }
        __syncthreads();                                   // gathers done
        if (np  >= 0) { s_t[np]  = e_t;  s_w[np]  = e_w; }
        if (np2 >= 0) { s_t[np2] = e2t; s_w[np2] = e2w; }
        __syncthreads();                                   // fixup visible

        float t_next = tEnd;
        if (next < cEnd) {
            float tx = s_t[next];
            int k = clampb((int)((tx - t0f) * BSCALE));
            int pk = pck[k];
            int bas = (pk >> 12) + baseOff, cn = pk & 0xfff;
            t_next = tx;
            if (bas >= next) {
                for (int q = bas; q < bas + cn; ++q) t_next = fminf(t_next, s_t[q]);
            }
        }

        float t_p = s_t[p];
        float w_p = valid ? s_w[p] : 0.f;
        float aw = w_p, awt = w_p * t_p;
        float xw  = wave_iscan_f32(aw);
        float xwt = wave_iscan_f32(awt);
        if (lane == 63) { s_fw[wid] = xw; s_fwt[wid] = xwt; }
        float tn = (p == PRE - 1) ? INFINITY
                 : (tid == TPB - 1) ? t_next : s_t[p + 1];
        __syncthreads();                                   // partials visible
        float W = cumW, WT = cumWT;
        for (int k2 = 0; k2 < wid; ++k2) { W += s_fw[k2]; WT += s_fwt[k2]; }
        W += xw; WT += xwt;
        cumW  += s_fw[0] + s_fw[1] + s_fw[2] + s_fw[3];
        cumWT += s_fwt[0] + s_fwt[1] + s_fwt[2] + s_fwt[3];

        float mc = INFINITY;
        if (valid && p < posValidEnd && W > 0.f) {
            float tmp = (theta + WT) * __builtin_amdgcn_rcpf(W);
            if (tmp >= t_p && tmp <= tn) mc = tmp;
        }
        mc = wave_min_f32(mc);
        if (lane == 0) s_red[wid] = mc;
        __syncthreads();                                   // mins visible
        mAll = fminf(mAll,
               fminf(fminf(s_red[0], s_red[1]), fminf(s_red[2], s_red[3])));
        if (mAll <= t_next) return true;
    }
    return false;
}

__global__ __launch_bounds__(TPB, 8) void equaltime_kernel(
    const float* __restrict__ spikes,     // [B][PRE]
    const float* __restrict__ weights,    // [PRE][POST]
    const float* __restrict__ delays,     // [PRE][POST]
    const float* __restrict__ thresholds, // [POST]
    float* __restrict__ out)              // [B][POST]
{
    __shared__ __align__(16) float s_t[PRE];   // 4 KB
    __shared__ __align__(16) float s_w[PRE];   // 4 KB
    __shared__ __align__(16) int   s_raw[NB];  // 2 KB raw counts (hist target)
    __shared__ __align__(16) int   s_pck[NB];  // 2 KB packed (off<<12|cnt)
    __shared__ float s_fw[4], s_fwt[4];
    __shared__ float s_red[4];

    const int tid  = threadIdx.x;
    const int lane = tid & 63;
    const int wid  = tid >> 6;

    // XCD-contiguous swizzle for weight/delay L2 locality
    const int bx   = blockIdx.x;
    const int sbx  = (bx & 7) * 512 + (bx >> 3);
    const int post = sbx >> 2;            // 4 WGs per post
    const int b0   = (sbx & 3) * BPW;
    const float theta = thresholds[post];

    float dly[EPT], wgt[EPT];
#pragma unroll
    for (int j = 0; j < EPT; ++j) {
        int pre = tid * EPT + j;
        dly[j] = delays[pre * POST + post];
        wgt[j] = weights[pre * POST + post];
    }

    // zero raw counts once (subsequent batches re-zero in the scatter slot)
    reinterpret_cast<int2*>(s_raw)[tid] = make_int2(0, 0);
    __syncthreads();

    for (int bi = 0; bi < BPW; ++bi) {
        const int b = b0 + bi;

        // ---- times; hist of t<TCUT into s_raw; min of the rest ----
        float4 sp = *reinterpret_cast<const float4*>(spikes + b * PRE + tid * EPT);
        float tv[EPT] = {sp.x + dly[0], sp.y + dly[1], sp.z + dly[2], sp.w + dly[3]};
        int bkt[EPT], rnk[EPT];
        float mloc = INFINITY;
#pragma unroll
        for (int j = 0; j < EPT; ++j) {
            int k = (int)(tv[j] * BSCALE);
            bkt[j] = k;
            if (k < NB) rnk[j] = atomicAdd(&s_raw[k], 1);
            else        mloc = fminf(mloc, tv[j]);
        }
        mloc = wave_min_f32(mloc);
        __syncthreads();                                   // B1: counts final

        if (lane == 0) s_red[wid] = mloc;                  // post-B1 write,
                                                           // post-B2 read
        const int N_low = scan_counts(s_raw, s_pck, lane, wid); // reads raw only
        __syncthreads();                                   // B2: pck + s_red visible

        const float minExcl = fminf(fminf(s_red[0], s_red[1]),
                                    fminf(s_red[2], s_red[3]));
        // ---- scatter included (reads s_pck); pad holes; wave1 zeroes s_raw ----
#pragma unroll
        for (int j = 0; j < EPT; ++j) {
            if (bkt[j] < NB) {
                int pos = (s_pck[bkt[j]] >> 12) + rnk[j];
                s_t[pos] = tv[j];
                s_w[pos] = wgt[j];
            }
        }
        if (wid == 1) {   // all s_raw reads completed at B2; contiguous writes
            reinterpret_cast<int4*>(s_raw)[lane]      = make_int4(0, 0, 0, 0);
            reinterpret_cast<int4*>(s_raw)[lane + 64] = make_int4(0, 0, 0, 0);
        }
        const int roundup = (N_low + CHUNK - 1) & ~(CHUNK - 1);
        int h = N_low + tid;
        if (h < roundup) { s_t[h] = minExcl; s_w[h] = 0.f; }
        __syncthreads();                                   // B3: scatter+zero visible

        // ---- epoch 0 (typically one chunk, exact early exit) ----
        float cumW = 0.f, cumWT = 0.f, mAll = INFINITY;
        bool done = run_epoch(s_t, s_w, s_pck, s_fw, s_fwt, s_red,
                              0, roundup, 0, N_low, 0.f, 0, minExcl, theta,
                              tid, lane, wid, cumW, cumWT, mAll);

        // ---- rare exact fallback: sort & process the excluded tail ----
        if (!done && N_low < PRE) {
            // s_raw is zeroed; s_pck is dead (epoch 0 finished). Reuse bkt/rnk.
#pragma unroll
            for (int j = 0; j < EPT; ++j) {
                if (bkt[j] >= NB) {
                    int k2 = clampb((int)((tv[j] - TCUTF) * BSCALE));
                    bkt[j] = NB + k2;          // remember tail bucket
                    rnk[j] = atomicAdd(&s_raw[k2], 1);
                }
            }
            __syncthreads();                               // counts final
            (void)scan_counts(s_raw, s_pck, lane, wid);    // wave 0 packs
            __syncthreads();                               // pck visible
#pragma unroll
            for (int j = 0; j < EPT; ++j) {
                if (bkt[j] >= NB) {
                    int k2 = bkt[j] - NB;
                    int pos = N_low + (s_pck[k2] >> 12) + rnk[j];
                    s_t[pos] = tv[j];
                    s_w[pos] = wgt[j];
                }
            }
            if (wid == 1) {   // re-zero raw for the next batch
                reinterpret_cast<int4*>(s_raw)[lane]      = make_int4(0, 0, 0, 0);
                reinterpret_cast<int4*>(s_raw)[lane + 64] = make_int4(0, 0, 0, 0);
            }
            __syncthreads();                               // scatter+zero visible
            run_epoch(s_t, s_w, s_pck, s_fw, s_fwt, s_red,
                      N_low & ~(CHUNK - 1), PRE, N_low, PRE,
                      TCUTF, N_low, INFINITY, theta,
                      tid, lane, wid, cumW, cumWT, mAll);
        }

        if (tid == 0) out[b * POST + post] = mAll;
        // No trailing barrier: next batch's hist atomics target s_raw, whose
        // zeroing was barrier-ordered before any post-barrier reader.
    }
}

extern "C" void kernel_launch(void* const* d_in, const int* in_sizes, int n_in,
                              void* d_out, int out_size, void* d_ws, size_t ws_size,
                              hipStream_t stream) {
    const float* spikes     = (const float*)d_in[0]; // [32,1024]
    const float* weights    = (const float*)d_in[1]; // [1024,1024]
    const float* delays     = (const float*)d_in[2]; // [1024,1024]
    const float* thresholds = (const float*)d_in[3]; // [1024]
    float* outp = (float*)d_out;                     // [32,1024]

    dim3 grid(POST * (B_TOT / BPW)); // 4096 workgroups
    dim3 block(TPB);
    equaltime_kernel<<<grid, block, 0, stream>>>(spikes, weights, delays, thresholds, outp);
}